// Round 16
// baseline (353.475 us; speedup 1.0000x reference)
//
#include <hip/hip_runtime.h>
#include <math.h>

#define BATCH 8
#define CIN 512
#define CO 256
#define HW 4096
#define KT 32
#define NSEG 4
#define SEGC 32            // y-chunks of 32 per segment (4*32*32 = 4096)

typedef unsigned short ushort_t;
typedef unsigned int uint_t;
typedef _Float16 v8h __attribute__((ext_vector_type(8)));
typedef _Float16 v4h __attribute__((ext_vector_type(4)));
typedef float v4f __attribute__((ext_vector_type(4)));
typedef float v16f __attribute__((ext_vector_type(16)));
typedef ushort_t u16x8 __attribute__((ext_vector_type(8)));

__device__ __forceinline__ ushort_t f2h(float f) {
  return __builtin_bit_cast(ushort_t, (_Float16)f);
}
__device__ __forceinline__ uint_t pkrtz(float lo, float hi) {
  return __builtin_bit_cast(uint_t, __builtin_amdgcn_cvt_pkrtz(lo, hi));
}
__device__ __forceinline__ v4f mfma16h(v8h a, v8h b, v4f c) {
  return __builtin_amdgcn_mfma_f32_16x16x32_f16(a, b, c, 0, 0, 0);
}
__device__ __forceinline__ v16f mfma32h(v8h a, v8h b, v16f c) {
  return __builtin_amdgcn_mfma_f32_32x32x16_f16(a, b, c, 0, 0, 0);
}
// pitch-512B tile (f16), granule-XOR by (row&31)  [32 granule classes]
__device__ __forceinline__ v8h lds_frag_h512w(const unsigned char* base, int row, int cb) {
  uint4 v = *(const uint4*)(base + row * 512 + (((cb) ^ (row & 31)) << 4));
  return __builtin_bit_cast(v8h, v);
}
// pitch-128B tile (f16), granule-XOR by (row&7)
__device__ __forceinline__ v8h lds_frag_h128(const unsigned char* base, int row, int cb) {
  uint4 v = *(const uint4*)(base + row * 128 + (((cb) ^ (row & 7)) << 4));
  return __builtin_bit_cast(v8h, v);
}
__device__ __forceinline__ void gll16(const void* g, void* l) {
  __builtin_amdgcn_global_load_lds(
      (const __attribute__((address_space(1))) unsigned int*)g,
      (__attribute__((address_space(3))) unsigned int*)l, 16, 0, 0);
}
// raw barriers with explicit waits
#define VMEM_BAR() do {                                            \
    asm volatile("s_waitcnt vmcnt(0) lgkmcnt(0)" ::: "memory");    \
    __builtin_amdgcn_sched_barrier(0);                             \
    __builtin_amdgcn_s_barrier();                                  \
    __builtin_amdgcn_sched_barrier(0);                             \
  } while (0)
#define LDS_BAR() do {                                             \
    asm volatile("s_waitcnt lgkmcnt(0)" ::: "memory");             \
    __builtin_amdgcn_sched_barrier(0);                             \
    __builtin_amdgcn_s_barrier();                                  \
    __builtin_amdgcn_sched_barrier(0);                             \
  } while (0)

// ===========================================================================
// W [CO][CIN] fp32 -> w_h f16
// ===========================================================================
__global__ __launch_bounds__(256) void k_w(
    const float* __restrict__ W, ushort_t* __restrict__ w_h) {
  int idx = blockIdx.x * 256 + threadIdx.x;
  size_t off = (size_t)idx * 8;
  float4 v0 = *(const float4*)&W[off];
  float4 v1 = *(const float4*)&W[off + 4];
  float f[8] = {v0.x, v0.y, v0.z, v0.w, v1.x, v1.y, v1.z, v1.w};
  u16x8 h;
#pragma unroll
  for (int j = 0; j < 8; ++j) h[j] = f2h(f[j]);
  *(u16x8*)&w_h[off] = h;
}

// ===========================================================================
// proj_t[b][x][o] = bias[o] + sum_c x[c][x]*W[o][c]  (f16 MFMA) -> f16
// Fused x-transpose (round-13 proven).
// ===========================================================================
__global__ __launch_bounds__(256, 2) void k_proj_mfma(
    const float* __restrict__ x, const ushort_t* __restrict__ w_h,
    const float* __restrict__ bias, ushort_t* __restrict__ proj_h) {
  __shared__ __align__(16) unsigned char L[2][128 * 128];  // Lx, Lw 16KB each
  __shared__ __align__(16) float Sx[64 * 132];             // 33KB scratch (pad 4)
  const int bid = blockIdx.x;
  const int b = bid & 7;
  const int rest = bid >> 3;
  const int xt = rest & 31;
  const int oh = rest >> 5;
  const int x0 = xt * 128;
  const int t = threadIdx.x;
  const int lane = t & 63, wave = t >> 6;

  v4f acc[2][8];
#pragma unroll
  for (int xf = 0; xf < 2; ++xf)
#pragma unroll
    for (int of = 0; of < 8; ++of) acc[xf][of] = (v4f){0.f, 0.f, 0.f, 0.f};

  float bias_of[8];
#pragma unroll
  for (int of = 0; of < 8; ++of)
    bias_of[of] = bias[oh * 128 + of * 16 + (lane & 15)];

  for (int ch = 0; ch < 8; ++ch) {
    const int c0 = ch * 64;
#pragma unroll
    for (int i = 0; i < 4; ++i) {
      int G = i * 256 + t;
      int r = G >> 3, sl = G & 7;
      int cg = (sl ^ (r & 7)) << 3;
      size_t wsrc = ((size_t)(oh * 128 + r)) * CIN + c0 + cg;
      gll16(&w_h[wsrc], &L[1][(unsigned)((i * 256 + wave * 64) << 4)]);
    }
    {
      int c = t >> 2, xq = t & 3;
      const float* src = &x[((size_t)b * CIN + c0 + c) * HW + x0 + xq * 32];
      float* dst = &Sx[c * 132 + xq * 32];
#pragma unroll
      for (int j = 0; j < 8; ++j)
        *(float4*)&dst[j * 4] = *(const float4*)&src[j * 4];
    }
    __syncthreads();
#pragma unroll
    for (int j = 0; j < 4; ++j) {
      int task = j * 256 + t;
      int xr = task >> 3, gs = task & 7;
      v8h h;
#pragma unroll
      for (int cc = 0; cc < 8; ++cc)
        h[cc] = (_Float16)Sx[(gs * 8 + cc) * 132 + xr];
      *(uint4*)&L[0][xr * 128 + ((gs ^ (xr & 7)) << 4)] =
          __builtin_bit_cast(uint4, h);
    }
    __syncthreads();
#pragma unroll
    for (int st = 0; st < 2; ++st) {
      int cb = st * 4 + (lane >> 4);
      v8h ah0 = lds_frag_h128(L[0], wave * 32 + (lane & 15), cb);
      v8h ah1 = lds_frag_h128(L[0], wave * 32 + 16 + (lane & 15), cb);
#pragma unroll
      for (int of = 0; of < 8; ++of) {
        v8h bh = lds_frag_h128(L[1], of * 16 + (lane & 15), cb);
        acc[0][of] = mfma16h(ah0, bh, acc[0][of]);
        acc[1][of] = mfma16h(ah1, bh, acc[1][of]);
      }
    }
    __syncthreads();
  }

  ushort_t* Th = (ushort_t*)&L[0][0];  // [128][128]
#pragma unroll
  for (int xf = 0; xf < 2; ++xf)
#pragma unroll
    for (int of = 0; of < 8; ++of)
#pragma unroll
      for (int r = 0; r < 4; ++r) {
        int x_loc = wave * 32 + xf * 16 + (lane >> 4) * 4 + r;
        int o_loc = of * 16 + (lane & 15);
        Th[x_loc * 128 + o_loc] = f2h(acc[xf][of][r] + bias_of[of]);
      }
  __syncthreads();
  {
    int row = t >> 1, half = t & 1;
    size_t off = ((size_t)b * HW + x0 + row) * CO + oh * 128 + half * 64;
#pragma unroll
    for (int j = 0; j < 8; ++j)
      *(uint4*)&proj_h[off + j * 8] =
          *(const uint4*)&Th[row * 128 + half * 64 + j * 8];
  }
}

// ===========================================================================
// pem [b][c][y] fp32 -> pem_t_h[b][y][c] f16 + pem_h[b][c][y] f16
// ===========================================================================
__global__ __launch_bounds__(256) void k_tr_pem(
    const float* __restrict__ pem,
    ushort_t* __restrict__ pem_t_h, ushort_t* __restrict__ pem_h) {
  __shared__ float T[64][65];
  const int y0 = blockIdx.x * 64;
  const int c0 = blockIdx.y * 64;
  const int b  = blockIdx.z;
  const int t  = threadIdx.x;
  const int cl = t >> 4;
  const int y4 = (t & 15) * 4;
#pragma unroll
  for (int r = 0; r < 4; ++r) {
    int c = c0 + r * 16 + cl;
    size_t off = ((size_t)b * CO + c) * HW + y0 + y4;
    float4 v = *(const float4*)&pem[off];
    ushort4 h;
    h.x = f2h(v.x); h.y = f2h(v.y); h.z = f2h(v.z); h.w = f2h(v.w);
    *(ushort4*)&pem_h[off] = h;
    T[r * 16 + cl][y4 + 0] = v.x;
    T[r * 16 + cl][y4 + 1] = v.y;
    T[r * 16 + cl][y4 + 2] = v.z;
    T[r * 16 + cl][y4 + 3] = v.w;
  }
  __syncthreads();
  {
    int yl = t >> 2;
    int cs = (t & 3) * 16;
    u16x8 h0, h1;
#pragma unroll
    for (int j = 0; j < 8; ++j) h0[j] = f2h(T[cs + j][yl]);
#pragma unroll
    for (int j = 0; j < 8; ++j) h1[j] = f2h(T[cs + 8 + j][yl]);
    size_t ro = ((size_t)b * HW + y0 + yl) * CO + c0 + cs;
    *(u16x8*)&pem_t_h[ro]     = h0;
    *(u16x8*)&pem_t_h[ro + 8] = h1;
  }
}

// ===========================================================================
// Stats: M/D over y, per segment (round-14 proven, wide pbuf swizzle).
// ===========================================================================
__global__ __launch_bounds__(512, 2) void k_stats_f16(
    const ushort_t* __restrict__ proj_h, const ushort_t* __restrict__ pem_t_h,
    float* __restrict__ m_seg, float* __restrict__ d_seg) {
  __shared__ __align__(16) unsigned char pbuf[2][32 * 512];  // 16 KB each
  const int id = blockIdx.x;
  const int b = id & 7;
  const int rest = id >> 3;
  const int xt = rest & 7;
  const int seg = rest >> 3;
  const int x0 = xt * 512;
  const int t = threadIdx.x;
  const int lane = t & 63, wave = t >> 6;
  const int xw = x0 + wave * 64;

  v8h Ah[4][8];
#pragma unroll
  for (int xf = 0; xf < 4; ++xf) {
    const size_t ro =
        ((size_t)b * HW + xw + xf * 16 + (lane & 15)) * CO + (lane >> 4) * 8;
#pragma unroll
    for (int st = 0; st < 8; ++st)
      Ah[xf][st] = __builtin_bit_cast(v8h, *(const uint4*)&proj_h[ro + st * 32]);
  }

  float m[4][4], d[4][4];
#pragma unroll
  for (int xf = 0; xf < 4; ++xf)
#pragma unroll
    for (int r = 0; r < 4; ++r) { m[xf][r] = -3.0e38f; d[xf][r] = 0.f; }

  auto stage = [&](int bufi, int tt) {
    const int yy0 = tt * 32;
#pragma unroll
    for (int i = 0; i < 2; ++i) {
      int G = i * 512 + t;
      int r = G >> 5, sl = G & 31;
      size_t so = ((size_t)b * HW + yy0 + r) * CO + ((sl ^ (r & 31)) << 3);
      unsigned lb = (unsigned)((i * 512 + wave * 64) << 4);
      gll16(&pem_t_h[so], &pbuf[bufi][lb]);
    }
  };

  const int tt0 = seg * SEGC;
  stage(0, tt0);
  __syncthreads();

  for (int tc = 0; tc < SEGC; ++tc) {
    if (tc + 1 < SEGC) stage((tc + 1) & 1, tt0 + tc + 1);

    const unsigned char* bp = pbuf[tc & 1];
    v4f acc[4][2];
#pragma unroll
    for (int xf = 0; xf < 4; ++xf)
#pragma unroll
      for (int yc = 0; yc < 2; ++yc) acc[xf][yc] = (v4f){0.f, 0.f, 0.f, 0.f};

#pragma unroll
    for (int st = 0; st < 8; ++st) {
#pragma unroll
      for (int yc = 0; yc < 2; ++yc) {
        v8h bh = lds_frag_h512w(bp, yc * 16 + (lane & 15), st * 4 + (lane >> 4));
        acc[0][yc] = mfma16h(Ah[0][st], bh, acc[0][yc]);
        acc[1][yc] = mfma16h(Ah[1][st], bh, acc[1][yc]);
        acc[2][yc] = mfma16h(Ah[2][st], bh, acc[2][yc]);
        acc[3][yc] = mfma16h(Ah[3][st], bh, acc[3][yc]);
      }
    }

#pragma unroll
    for (int xf = 0; xf < 4; ++xf) {
      float mx8 = fmaxf(fmaxf(fmaxf(acc[xf][0][0], acc[xf][0][1]),
                              fmaxf(acc[xf][0][2], acc[xf][0][3])),
                        fmaxf(fmaxf(acc[xf][1][0], acc[xf][1][1]),
                              fmaxf(acc[xf][1][2], acc[xf][1][3])));
      float minm = fminf(fminf(m[xf][0], m[xf][1]), fminf(m[xf][2], m[xf][3]));
      if (__any(mx8 > minm + 8.0f)) {
#pragma unroll
        for (int r = 0; r < 4; ++r) {
          float rm = fmaxf(acc[xf][0][r], acc[xf][1][r]);
          rm = fmaxf(rm, __shfl_xor(rm, 1));
          rm = fmaxf(rm, __shfl_xor(rm, 2));
          rm = fmaxf(rm, __shfl_xor(rm, 4));
          rm = fmaxf(rm, __shfl_xor(rm, 8));
          float mn = fmaxf(m[xf][r], rm);
          d[xf][r] *= __expf(m[xf][r] - mn);
          m[xf][r] = mn;
        }
      }
#pragma unroll
      for (int r = 0; r < 4; ++r)
        d[xf][r] += __expf(acc[xf][0][r] - m[xf][r]) +
                    __expf(acc[xf][1][r] - m[xf][r]);
    }
    __syncthreads();
  }

#pragma unroll
  for (int xf = 0; xf < 4; ++xf) {
    float dv[4];
#pragma unroll
    for (int r = 0; r < 4; ++r) {
      float v = d[xf][r];
      v += __shfl_xor(v, 1);
      v += __shfl_xor(v, 2);
      v += __shfl_xor(v, 4);
      v += __shfl_xor(v, 8);
      dv[r] = v;
    }
    if ((lane & 15) == 0) {
      size_t o = ((size_t)(b * NSEG + seg)) * HW + xw + xf * 16 + (lane >> 4) * 4;
      *(float4*)&m_seg[o] = make_float4(m[xf][0], m[xf][1], m[xf][2], m[xf][3]);
      *(float4*)&d_seg[o] = make_float4(dv[0], dv[1], dv[2], dv[3]);
    }
  }
}

// ===========================================================================
// Merge segments -> Cx = M + log(D)
// ===========================================================================
__global__ __launch_bounds__(256) void k_red2(
    const float* __restrict__ m_seg, const float* __restrict__ d_seg,
    float* __restrict__ Cx) {
  int idx = blockIdx.x * 256 + threadIdx.x;
  int b = idx >> 12;
  int xx = idx & 4095;
  float ms[NSEG], ds[NSEG];
  float mm = -3.0e38f;
#pragma unroll
  for (int s = 0; s < NSEG; ++s) {
    ms[s] = m_seg[((size_t)(b * NSEG + s)) * HW + xx];
    ds[s] = d_seg[((size_t)(b * NSEG + s)) * HW + xx];
    mm = fmaxf(mm, ms[s]);
  }
  float dd = 0.f;
#pragma unroll
  for (int s = 0; s < NSEG; ++s) dd += ds[s] * __expf(ms[s] - mm);
  Cx[(size_t)b * HW + xx] = mm + __logf(dd);
}

// ===========================================================================
// Fused out-pass v3: E kept IN REGISTERS (cvt_pkrtz + shfl_xor(32) repack) —
// no Le tile, ONE barrier per 64x chunk. Wave owns (32x-half, 32y-slice)
// for both S and PV; PV partials pair-summed in LDS at the epilogue.
// 512 thr (8 waves: half=wave&1, ys=wave>>1), y-tile 128, x-chunks of 64.
// grid: 8b * 32yt = 256 blocks. LDS 128 KB -> 1 block/CU, 2 waves/SIMD.
// ===========================================================================
__global__ __launch_bounds__(512, 2) void k_fused(
    const ushort_t* __restrict__ proj_h, const ushort_t* __restrict__ pem_t_h,
    const ushort_t* __restrict__ pem_h, const float* __restrict__ Cx,
    float* __restrict__ out) {
  __shared__ __align__(16) unsigned char SMEM[128 * 1024];
  unsigned char (*Lp)[64 * 512] = (unsigned char (*)[64 * 512])(SMEM);
  unsigned char (*Lk)[256 * 128] = (unsigned char (*)[256 * 128])(SMEM + 64 * 1024);
  const int id = blockIdx.x;
  const int b = id & 7;
  const int yt = id >> 3;
  const int y0 = yt * 128;
  const int t = threadIdx.x;
  const int lane = t & 63, wave = t >> 6;
  const int l31 = lane & 31, lh = lane >> 5;
  const int half = wave & 1, ys = wave >> 1;

  // B-res for S: wave's 32y slice of pem_t, K=256: 16 frags (64 VGPR)
  v8h Bres[16];
  {
    const size_t ro = ((size_t)b * HW + y0 + ys * 32 + l31) * CO + lh * 8;
#pragma unroll
    for (int st = 0; st < 16; ++st)
      Bres[st] = __builtin_bit_cast(v8h, *(const uint4*)&pem_t_h[ro + st * 16]);
  }

  v16f pv[8];
#pragma unroll
  for (int kt = 0; kt < 8; ++kt)
#pragma unroll
    for (int r = 0; r < 16; ++r) pv[kt][r] = 0.f;

  auto stage = [&](int bufi, int xt) {
    const int x0s = xt * 64;
    // Lp: [64x][512B] wide (r&31) source swizzle
#pragma unroll
    for (int i = 0; i < 4; ++i) {
      int G = i * 512 + t;
      int r = G >> 5, sl = G & 31;
      size_t so = ((size_t)b * HW + x0s + r) * CO + ((sl ^ (r & 31)) << 3);
      gll16(&proj_h[so], &Lp[bufi][(unsigned)((i * 512 + wave * 64) << 4)]);
    }
    // Lk: [256k][128B]
#pragma unroll
    for (int i = 0; i < 4; ++i) {
      int G = i * 512 + t;
      int r = G >> 3, sl = G & 7;
      size_t so = ((size_t)b * CO + r) * HW + x0s + ((sl ^ (r & 7)) << 3);
      gll16(&pem_h[so], &Lk[bufi][(unsigned)((i * 512 + wave * 64) << 4)]);
    }
  };

  stage(0, 0);

  for (int xt = 0; xt < 64; ++xt) {
    const int cur = xt & 1;
    const int x0 = xt * 64;
    VMEM_BAR();   // buf[cur] ready; all waves' prior ds_reads retired

    if (xt + 1 < 64) stage(cur ^ 1, xt + 1);  // full-chunk latency budget

    // ---- S: wave's [32x(half)][32y(ys)] tile, A from Lp, B in regs ----
    v16f s;
#pragma unroll
    for (int r = 0; r < 16; ++r) s[r] = 0.f;
    __builtin_amdgcn_s_setprio(1);
#pragma unroll
    for (int st = 0; st < 16; ++st) {
      v8h a = lds_frag_h512w(Lp[cur], half * 32 + l31, st * 2 + lh);
      s = mfma32h(a, Bres[st], s);
    }
    __builtin_amdgcn_s_setprio(0);

    // ---- E in registers: exp -> pkrtz pairs -> cross-half shfl repack ----
    // s[r] is S at x = (r&3) + 8*(r>>2) + 4*lh (within wave's 32x), y = l31.
    uint_t d[8];
    {
      const float* cxb = &Cx[(size_t)b * HW + x0 + half * 32 + 4 * lh];
#pragma unroll
      for (int q = 0; q < 4; ++q) {
        float4 c4 = *(const float4*)&cxb[8 * q];
        d[2 * q]     = pkrtz(__expf(s[4 * q + 0] - c4.x),
                             __expf(s[4 * q + 1] - c4.y));
        d[2 * q + 1] = pkrtz(__expf(s[4 * q + 2] - c4.z),
                             __expf(s[4 * q + 3] - c4.w));
      }
    }
    uint_t p[8];
#pragma unroll
    for (int j = 0; j < 8; ++j)
      p[j] = (uint_t)__shfl_xor((int)d[j], 32);
    uint4 w0, w1;
    if (lh == 0) {
      w0 = make_uint4(d[0], d[1], p[0], p[1]);
      w1 = make_uint4(d[4], d[5], p[4], p[5]);
    } else {
      w0 = make_uint4(p[2], p[3], d[2], d[3]);
      w1 = make_uint4(p[6], p[7], d[6], d[7]);
    }
    v8h B0 = __builtin_bit_cast(v8h, w0);   // E k-step 0 (x 0..15 of half)
    v8h B1 = __builtin_bit_cast(v8h, w1);   // E k-step 1 (x 16..31)

    // ---- PV: out[256k][32y] over wave's 32x; A from Lk, B = E regs ----
    __builtin_amdgcn_s_setprio(1);
#pragma unroll
    for (int kt = 0; kt < 8; ++kt) {
      v8h a0 = lds_frag_h128(Lk[cur], kt * 32 + l31, half * 4 + 0 + lh);
      pv[kt] = mfma32h(a0, B0, pv[kt]);
      v8h a1 = lds_frag_h128(Lk[cur], kt * 32 + l31, half * 4 + 2 + lh);
      pv[kt] = mfma32h(a1, B1, pv[kt]);
    }
    __builtin_amdgcn_s_setprio(0);
  }

  // ---- epilogue: pair-sum halves via LDS, then store ----
  LDS_BAR();    // last PV reads retired on all waves
  {
    float* red = (float*)SMEM;   // 4 regions of 32KB (per ys)
    if (half == 1) {
      float* dst = red + (size_t)ys * 8192;
#pragma unroll
      for (int kt = 0; kt < 8; ++kt)
#pragma unroll
        for (int r = 0; r < 16; ++r)
          dst[(kt * 16 + r) * 64 + lane] = pv[kt][r];
    }
    __syncthreads();
    if (half == 0) {
      const float* src = red + (size_t)ys * 8192;
#pragma unroll
      for (int kt = 0; kt < 8; ++kt) {
#pragma unroll
        for (int r = 0; r < 16; ++r) {
          float v = pv[kt][r] + src[(kt * 16 + r) * 64 + lane];
          int k = kt * 32 + (r & 3) + 8 * (r >> 2) + 4 * lh;
          int y = y0 + ys * 32 + l31;
          out[((size_t)b * CO + k) * HW + y] = v;
        }
      }
    }
  }
}

// ===========================================================================
// fp32 fallback path (only if ws is too small)
// ===========================================================================
__global__ __launch_bounds__(256) void k_proj(
    const float* __restrict__ x, const float* __restrict__ W,
    const float* __restrict__ bias, float* __restrict__ proj) {
  __shared__ float As[KT][68];
  __shared__ float Bs[KT][68];
  const int i0 = blockIdx.x * 64;
  const int o0 = blockIdx.y * 64;
  const int b  = blockIdx.z;
  const int t  = threadIdx.x;
  const int tx = t & 15, ty = t >> 4;
  const float* xb = x + (size_t)b * CIN * HW;
  float acc[4][4] = {};
  for (int c0 = 0; c0 < CIN; c0 += KT) {
#pragma unroll
    for (int l = 0; l < 8; ++l) {
      int idx = t + l * 256;
      int o = idx >> 5;
      int c = idx & 31;
      As[c][o] = W[(size_t)(o0 + o) * CIN + c0 + c];
    }
#pragma unroll
    for (int l = 0; l < 2; ++l) {
      int idx4 = t + l * 256;
      int c = idx4 >> 4;
      int i4 = idx4 & 15;
      *(float4*)&Bs[c][i4 * 4] =
          *(const float4*)&xb[(size_t)(c0 + c) * HW + i0 + i4 * 4];
    }
    __syncthreads();
#pragma unroll
    for (int c = 0; c < KT; ++c) {
      float4 a  = *(const float4*)&As[c][tx * 4];
      float4 bv = *(const float4*)&Bs[c][ty * 4];
      float av[4] = {a.x, a.y, a.z, a.w};
      float bb[4] = {bv.x, bv.y, bv.z, bv.w};
#pragma unroll
      for (int u = 0; u < 4; ++u)
#pragma unroll
        for (int v = 0; v < 4; ++v) acc[u][v] += av[u] * bb[v];
    }
    __syncthreads();
  }
  float* pbout = proj + (size_t)b * CO * HW;
#pragma unroll
  for (int u = 0; u < 4; ++u) {
    int o = o0 + tx * 4 + u;
    float bsv = bias[o];
    float4 r;
    r.x = acc[u][0] + bsv; r.y = acc[u][1] + bsv;
    r.z = acc[u][2] + bsv; r.w = acc[u][3] + bsv;
    *(float4*)&pbout[(size_t)o * HW + i0 + ty * 4] = r;
  }
}

__global__ __launch_bounds__(256) void k_stats(
    const float* __restrict__ proj, const float* __restrict__ pem,
    float* __restrict__ Mx, float* __restrict__ Dinv) {
  __shared__ float As[KT][68];
  __shared__ float Bs[KT][68];
  __shared__ float MsS[64][17];
  __shared__ float DsS[64][17];
  const int x0 = blockIdx.x * 64;
  const int b  = blockIdx.y;
  const int t  = threadIdx.x;
  const int tx = t & 15, ty = t >> 4;
  const float* pj = proj + (size_t)b * CO * HW;
  const float* pe = pem + (size_t)b * CO * HW;
  float m[4], d[4];
#pragma unroll
  for (int u = 0; u < 4; ++u) { m[u] = -3.0e38f; d[u] = 0.f; }
  for (int y0 = 0; y0 < HW; y0 += 64) {
    float s[4][4] = {};
    for (int c0 = 0; c0 < CO; c0 += KT) {
#pragma unroll
      for (int l = 0; l < 2; ++l) {
        int idx4 = t + l * 256;
        int c = idx4 >> 4, w4 = idx4 & 15;
        *(float4*)&As[c][w4 * 4] =
            *(const float4*)&pj[(size_t)(c0 + c) * HW + x0 + w4 * 4];
        *(float4*)&Bs[c][w4 * 4] =
            *(const float4*)&pe[(size_t)(c0 + c) * HW + y0 + w4 * 4];
      }
      __syncthreads();
#pragma unroll
      for (int c = 0; c < KT; ++c) {
        float4 a  = *(const float4*)&As[c][tx * 4];
        float4 bv = *(const float4*)&Bs[c][ty * 4];
        float av[4] = {a.x, a.y, a.z, a.w};
        float bb[4] = {bv.x, bv.y, bv.z, bv.w};
#pragma unroll
        for (int u = 0; u < 4; ++u)
#pragma unroll
          for (int v = 0; v < 4; ++v) s[u][v] += av[u] * bb[v];
      }
      __syncthreads();
    }
#pragma unroll
    for (int u = 0; u < 4; ++u) {
      float mv = fmaxf(fmaxf(s[u][0], s[u][1]), fmaxf(s[u][2], s[u][3]));
      if (mv > m[u]) { d[u] *= __expf(m[u] - mv); m[u] = mv; }
      d[u] += __expf(s[u][0] - m[u]) + __expf(s[u][1] - m[u]) +
              __expf(s[u][2] - m[u]) + __expf(s[u][3] - m[u]);
    }
  }
#pragma unroll
  for (int u = 0; u < 4; ++u) { MsS[tx * 4 + u][ty] = m[u]; DsS[tx * 4 + u][ty] = d[u]; }
  __syncthreads();
  if (t < 64) {
    float mm = -3.0e38f;
#pragma unroll
    for (int i = 0; i < 16; ++i) mm = fmaxf(mm, MsS[t][i]);
    float dd = 0.f;
#pragma unroll
    for (int i = 0; i < 16; ++i) dd += DsS[t][i] * __expf(MsS[t][i] - mm);
    Mx[(size_t)b * HW + x0 + t]   = mm;
    Dinv[(size_t)b * HW + x0 + t] = 1.0f / dd;
  }
}

__global__ __launch_bounds__(256) void k_out(
    const float* __restrict__ proj, const float* __restrict__ pem,
    const float* __restrict__ Mx, const float* __restrict__ Dinv,
    float* __restrict__ out) {
  __shared__ float As[KT][68];
  __shared__ float Bs[KT][68];
  __shared__ float E[64][68];
  const int y0 = blockIdx.x * 64;
  const int b  = blockIdx.y;
  const int t  = threadIdx.x;
  const int tx = t & 15, ty = t >> 4;
  const int kg = t >> 3, yg = t & 7;
  const float* pj = proj + (size_t)b * CO * HW;
  const float* pe = pem + (size_t)b * CO * HW;
  const float* Mb = Mx + (size_t)b * HW;
  const float* Db = Dinv + (size_t)b * HW;
  float acc[8][8] = {};
  for (int x0 = 0; x0 < HW; x0 += 64) {
    float s[4][4] = {};
    for (int c0 = 0; c0 < CO; c0 += KT) {
#pragma unroll
      for (int l = 0; l < 2; ++l) {
        int idx4 = t + l * 256;
        int c = idx4 >> 4, w4 = idx4 & 15;
        *(float4*)&As[c][w4 * 4] =
            *(const float4*)&pj[(size_t)(c0 + c) * HW + x0 + w4 * 4];
        *(float4*)&Bs[c][w4 * 4] =
            *(const float4*)&pe[(size_t)(c0 + c) * HW + y0 + w4 * 4];
      }
      __syncthreads();
#pragma unroll
      for (int c = 0; c < KT; ++c) {
        float4 a  = *(const float4*)&As[c][tx * 4];
        float4 bv = *(const float4*)&Bs[c][ty * 4];
        float av[4] = {a.x, a.y, a.z, a.w};
        float bb[4] = {bv.x, bv.y, bv.z, bv.w};
#pragma unroll
        for (int u = 0; u < 4; ++u)
#pragma unroll
          for (int v = 0; v < 4; ++v) s[u][v] += av[u] * bb[v];
      }
      __syncthreads();
    }
#pragma unroll
    for (int u = 0; u < 4; ++u) {
      int xr = x0 + tx * 4 + u;
      float mm = Mb[xr];
      float di = Db[xr];
      E[tx * 4 + u][ty * 4 + 0] = __expf(s[u][0] - mm) * di;
      E[tx * 4 + u][ty * 4 + 1] = __expf(s[u][1] - mm) * di;
      E[tx * 4 + u][ty * 4 + 2] = __expf(s[u][2] - mm) * di;
      E[tx * 4 + u][ty * 4 + 3] = __expf(s[u][3] - mm) * di;
    }
    __syncthreads();
    for (int xi = 0; xi < 64; xi += 4) {
      float4 p[8];
#pragma unroll
      for (int u = 0; u < 8; ++u)
        p[u] = *(const float4*)&pe[(size_t)(kg * 8 + u) * HW + x0 + xi];
#pragma unroll
      for (int j = 0; j < 4; ++j) {
        float4 e0 = *(const float4*)&E[xi + j][yg * 8];
        float4 e1 = *(const float4*)&E[xi + j][yg * 8 + 4];
        float evv[8] = {e0.x, e0.y, e0.z, e0.w, e1.x, e1.y, e1.z, e1.w};
#pragma unroll
        for (int u = 0; u < 8; ++u) {
          float a = (j == 0) ? p[u].x : (j == 1) ? p[u].y : (j == 2) ? p[u].z : p[u].w;
#pragma unroll
          for (int v = 0; v < 8; ++v) acc[u][v] += a * evv[v];
        }
      }
    }
    __syncthreads();
  }
#pragma unroll
  for (int u = 0; u < 8; ++u) {
    int k = kg * 8 + u;
    float4 r0, r1;
    r0.x = acc[u][0]; r0.y = acc[u][1]; r0.z = acc[u][2]; r0.w = acc[u][3];
    r1.x = acc[u][4]; r1.y = acc[u][5]; r1.z = acc[u][6]; r1.w = acc[u][7];
    float* ob = out + ((size_t)b * CO + k) * HW + y0 + yg * 8;
    *(float4*)&ob[0] = r0;
    *(float4*)&ob[4] = r1;
  }
}

// ===========================================================================
extern "C" void kernel_launch(void* const* d_in, const int* in_sizes, int n_in,
                              void* d_out, int out_size, void* d_ws, size_t ws_size,
                              hipStream_t stream) {
  const float* x    = (const float*)d_in[0];
  const float* pem  = (const float*)d_in[1];
  const float* W    = (const float*)d_in[2];
  const float* bias = (const float*)d_in[3];
  float* out = (float*)d_out;

  const size_t NS   = (size_t)BATCH * HW * CO;       // 8.39M
  const size_t NS2  = (size_t)BATCH * HW * CIN;      // 16.78M
  const size_t HWB  = (size_t)BATCH * HW;            // 32768
  const size_t SEGN = (size_t)BATCH * NSEG * HW;     // 131072
  const size_t WN   = (size_t)CO * CIN;              // 131072

  unsigned char* basep = (unsigned char*)d_ws;
  ushort_t* proj_h   = (ushort_t*)basep;
  ushort_t* pem_t_h  = proj_h + NS;
  ushort_t* pem_h    = pem_t_h + NS;
  float*    Cxp      = (float*)(pem_h + NS);
  float*    m_seg    = Cxp + HWB;
  float*    d_seg    = m_seg + SEGN;
  ushort_t* xt_h     = (ushort_t*)(d_seg + SEGN);    // region kept (unused)
  ushort_t* w_h      = xt_h + NS2;

  const size_t need = 3 * NS * 2 + HWB * 4 + 2 * SEGN * 4 + NS2 * 2 + WN * 2;

  if (ws_size < need) {
    // fp32 fallback
    float* proj = (float*)d_ws;
    float* Mx2  = proj + NS;
    float* Di2  = Mx2 + HWB;
    const size_t need_f = (NS + 2 * HWB) * sizeof(float);
    if (ws_size < need_f) return;
    k_proj <<<dim3(HW / 64, CO / 64, BATCH), 256, 0, stream>>>(x, W, bias, proj);
    k_stats<<<dim3(HW / 64, BATCH),          256, 0, stream>>>(proj, pem, Mx2, Di2);
    k_out  <<<dim3(HW / 64, BATCH),          256, 0, stream>>>(proj, pem, Mx2, Di2, out);
    return;
  }

  k_w<<<64, 256, 0, stream>>>(W, w_h);
  k_proj_mfma<<<512, 256, 0, stream>>>(x, w_h, bias, proj_h);
  k_tr_pem<<<dim3(HW / 64, CO / 64, BATCH), 256, 0, stream>>>(pem, pem_t_h, pem_h);

  k_stats_f16<<<256, 512, 0, stream>>>(proj_h, pem_t_h, m_seg, d_seg);
  k_red2<<<128, 256, 0, stream>>>(m_seg, d_seg, Cxp);
  k_fused<<<256, 512, 0, stream>>>(proj_h, pem_t_h, pem_h, Cxp, out);
}

// Round 17
// 312.863 us; speedup vs baseline: 1.1298x; 1.1298x over previous
//
#include <hip/hip_runtime.h>
#include <math.h>

#define BATCH 8
#define CIN 512
#define CO 256
#define HW 4096
#define KT 32
#define NSEG 4
#define SEGC 32            // y-chunks of 32 per segment (4*32*32 = 4096)

typedef unsigned short ushort_t;
typedef unsigned int uint_t;
typedef _Float16 v8h __attribute__((ext_vector_type(8)));
typedef _Float16 v4h __attribute__((ext_vector_type(4)));
typedef float v4f __attribute__((ext_vector_type(4)));
typedef float v16f __attribute__((ext_vector_type(16)));
typedef ushort_t u16x8 __attribute__((ext_vector_type(8)));

__device__ __forceinline__ ushort_t f2h(float f) {
  return __builtin_bit_cast(ushort_t, (_Float16)f);
}
__device__ __forceinline__ v4f mfma16h(v8h a, v8h b, v4f c) {
  return __builtin_amdgcn_mfma_f32_16x16x32_f16(a, b, c, 0, 0, 0);
}
__device__ __forceinline__ v16f mfma32h(v8h a, v8h b, v16f c) {
  return __builtin_amdgcn_mfma_f32_32x32x16_f16(a, b, c, 0, 0, 0);
}
// pitch-512B tile (f16), granule-XOR by (row&7)
__device__ __forceinline__ v8h lds_frag_h512(const unsigned char* base, int row, int cb) {
  uint4 v = *(const uint4*)(base + row * 512 + (((cb) ^ (row & 7)) << 4));
  return __builtin_bit_cast(v8h, v);
}
// pitch-128B tile (f16), granule-XOR by (row&7)
__device__ __forceinline__ v8h lds_frag_h128(const unsigned char* base, int row, int cb) {
  uint4 v = *(const uint4*)(base + row * 128 + (((cb) ^ (row & 7)) << 4));
  return __builtin_bit_cast(v8h, v);
}
__device__ __forceinline__ void gll16(const void* g, void* l) {
  __builtin_amdgcn_global_load_lds(
      (const __attribute__((address_space(1))) unsigned int*)g,
      (__attribute__((address_space(3))) unsigned int*)l, 16, 0, 0);
}
// raw barriers with explicit waits (T4: keep gll16 in flight across E barrier)
#define VMEM_BAR() do {                                            \
    asm volatile("s_waitcnt vmcnt(0) lgkmcnt(0)" ::: "memory");    \
    __builtin_amdgcn_sched_barrier(0);                             \
    __builtin_amdgcn_s_barrier();                                  \
    __builtin_amdgcn_sched_barrier(0);                             \
  } while (0)
#define LDS_BAR() do {                                             \
    asm volatile("s_waitcnt lgkmcnt(0)" ::: "memory");             \
    __builtin_amdgcn_sched_barrier(0);                             \
    __builtin_amdgcn_s_barrier();                                  \
    __builtin_amdgcn_sched_barrier(0);                             \
  } while (0)

// ===========================================================================
// W [CO][CIN] fp32 -> w_h f16
// ===========================================================================
__global__ __launch_bounds__(256) void k_w(
    const float* __restrict__ W, ushort_t* __restrict__ w_h) {
  int idx = blockIdx.x * 256 + threadIdx.x;
  size_t off = (size_t)idx * 8;
  float4 v0 = *(const float4*)&W[off];
  float4 v1 = *(const float4*)&W[off + 4];
  float f[8] = {v0.x, v0.y, v0.z, v0.w, v1.x, v1.y, v1.z, v1.w};
  u16x8 h;
#pragma unroll
  for (int j = 0; j < 8; ++j) h[j] = f2h(f[j]);
  *(u16x8*)&w_h[off] = h;
}

// ===========================================================================
// x [b][c][i] fp32 -> x_t [b][i][c] f16 (transposed, coalesced)
// ===========================================================================
__global__ __launch_bounds__(256) void k_tr_x(
    const float* __restrict__ x, ushort_t* __restrict__ xt_h) {
  __shared__ float T[64][65];
  const int i0 = blockIdx.x * 64;
  const int c0 = blockIdx.y * 64;
  const int b  = blockIdx.z;
  const int t  = threadIdx.x;
  const int cl = t >> 4;
  const int i4 = (t & 15) * 4;
#pragma unroll
  for (int r = 0; r < 4; ++r) {
    int c = c0 + r * 16 + cl;
    size_t off = ((size_t)b * CIN + c) * HW + i0 + i4;
    float4 v = *(const float4*)&x[off];
    T[r * 16 + cl][i4 + 0] = v.x;
    T[r * 16 + cl][i4 + 1] = v.y;
    T[r * 16 + cl][i4 + 2] = v.z;
    T[r * 16 + cl][i4 + 3] = v.w;
  }
  __syncthreads();
  {
    int il = t >> 2;
    int cs = (t & 3) * 16;
    u16x8 h0, h1;
#pragma unroll
    for (int j = 0; j < 8; ++j) h0[j] = f2h(T[cs + j][il]);
#pragma unroll
    for (int j = 0; j < 8; ++j) h1[j] = f2h(T[cs + 8 + j][il]);
    size_t ro = ((size_t)b * HW + i0 + il) * CIN + c0 + cs;
    *(u16x8*)&xt_h[ro]     = h0;
    *(u16x8*)&xt_h[ro + 8] = h1;
  }
}

// ===========================================================================
// proj_t[b][x][o] = bias[o] + sum_c x_t[b][x][c]*W[o][c]  (f16 MFMA) -> f16
// grid: 8b*32xt*2oh = 512 blocks, 256 thr. Tile 128x*128o, BK=64.
// ===========================================================================
__global__ __launch_bounds__(256, 2) void k_proj_mfma(
    const ushort_t* __restrict__ xt_h, const ushort_t* __restrict__ w_h,
    const float* __restrict__ bias, ushort_t* __restrict__ proj_h) {
  __shared__ __align__(16) unsigned char L[2][128 * 128];  // Lx, Lw 16KB each
  const int bid = blockIdx.x;
  const int b = bid & 7;
  const int rest = bid >> 3;
  const int xt = rest & 31;
  const int oh = rest >> 5;
  const int x0 = xt * 128;
  const int t = threadIdx.x;
  const int lane = t & 63, wave = t >> 6;

  v4f acc[2][8];
#pragma unroll
  for (int xf = 0; xf < 2; ++xf)
#pragma unroll
    for (int of = 0; of < 8; ++of) acc[xf][of] = (v4f){0.f, 0.f, 0.f, 0.f};

  float bias_of[8];
#pragma unroll
  for (int of = 0; of < 8; ++of)
    bias_of[of] = bias[oh * 128 + of * 16 + (lane & 15)];

  for (int ch = 0; ch < 8; ++ch) {
    const int c0 = ch * 64;
#pragma unroll
    for (int i = 0; i < 4; ++i) {
      int G = i * 256 + t;
      int r = G >> 3, sl = G & 7;
      int cg = (sl ^ (r & 7)) << 3;
      size_t xsrc = ((size_t)b * HW + x0 + r) * CIN + c0 + cg;
      size_t wsrc = ((size_t)(oh * 128 + r)) * CIN + c0 + cg;
      unsigned lb = (unsigned)((i * 256 + wave * 64) << 4);
      gll16(&xt_h[xsrc], &L[0][lb]);
      gll16(&w_h[wsrc],  &L[1][lb]);
    }
    __syncthreads();
#pragma unroll
    for (int st = 0; st < 2; ++st) {
      int cb = st * 4 + (lane >> 4);
      v8h ah0 = lds_frag_h128(L[0], wave * 32 + (lane & 15), cb);
      v8h ah1 = lds_frag_h128(L[0], wave * 32 + 16 + (lane & 15), cb);
#pragma unroll
      for (int of = 0; of < 8; ++of) {
        v8h bh = lds_frag_h128(L[1], of * 16 + (lane & 15), cb);
        acc[0][of] = mfma16h(ah0, bh, acc[0][of]);
        acc[1][of] = mfma16h(ah1, bh, acc[1][of]);
      }
    }
    __syncthreads();
  }

  // epilogue: bias + f16 -> LDS transpose -> coalesced store
  ushort_t* Th = (ushort_t*)&L[0][0];  // [128][128] = 32KB spans L
#pragma unroll
  for (int xf = 0; xf < 2; ++xf)
#pragma unroll
    for (int of = 0; of < 8; ++of)
#pragma unroll
      for (int r = 0; r < 4; ++r) {
        int x_loc = wave * 32 + xf * 16 + (lane >> 4) * 4 + r;
        int o_loc = of * 16 + (lane & 15);
        Th[x_loc * 128 + o_loc] = f2h(acc[xf][of][r] + bias_of[of]);
      }
  __syncthreads();
  {
    int row = t >> 1, half = t & 1;
    size_t off = ((size_t)b * HW + x0 + row) * CO + oh * 128 + half * 64;
#pragma unroll
    for (int j = 0; j < 8; ++j)
      *(uint4*)&proj_h[off + j * 8] =
          *(const uint4*)&Th[row * 128 + half * 64 + j * 8];
  }
}

// ===========================================================================
// pem [b][c][y] fp32 -> pem_t_h[b][y][c] f16 + pem_h[b][c][y] f16
// ===========================================================================
__global__ __launch_bounds__(256) void k_tr_pem(
    const float* __restrict__ pem,
    ushort_t* __restrict__ pem_t_h, ushort_t* __restrict__ pem_h) {
  __shared__ float T[64][65];
  const int y0 = blockIdx.x * 64;
  const int c0 = blockIdx.y * 64;
  const int b  = blockIdx.z;
  const int t  = threadIdx.x;
  const int cl = t >> 4;
  const int y4 = (t & 15) * 4;
#pragma unroll
  for (int r = 0; r < 4; ++r) {
    int c = c0 + r * 16 + cl;
    size_t off = ((size_t)b * CO + c) * HW + y0 + y4;
    float4 v = *(const float4*)&pem[off];
    ushort4 h;
    h.x = f2h(v.x); h.y = f2h(v.y); h.z = f2h(v.z); h.w = f2h(v.w);
    *(ushort4*)&pem_h[off] = h;
    T[r * 16 + cl][y4 + 0] = v.x;
    T[r * 16 + cl][y4 + 1] = v.y;
    T[r * 16 + cl][y4 + 2] = v.z;
    T[r * 16 + cl][y4 + 3] = v.w;
  }
  __syncthreads();
  {
    int yl = t >> 2;
    int cs = (t & 3) * 16;
    u16x8 h0, h1;
#pragma unroll
    for (int j = 0; j < 8; ++j) h0[j] = f2h(T[cs + j][yl]);
#pragma unroll
    for (int j = 0; j < 8; ++j) h1[j] = f2h(T[cs + 8 + j][yl]);
    size_t ro = ((size_t)b * HW + y0 + yl) * CO + c0 + cs;
    *(u16x8*)&pem_t_h[ro]     = h0;
    *(u16x8*)&pem_t_h[ro + 8] = h1;
  }
}

// ===========================================================================
// Stats: M/D over y, per segment. 512 thr (8 waves), x-tile 512 (64x/wave,
// A-res 4x8 frags). grid: 8b * 8xt * 4seg = 256 blocks.
// ===========================================================================
__global__ __launch_bounds__(512, 2) void k_stats_f16(
    const ushort_t* __restrict__ proj_h, const ushort_t* __restrict__ pem_t_h,
    float* __restrict__ m_seg, float* __restrict__ d_seg) {
  __shared__ __align__(16) unsigned char pbuf[2][32 * 512];  // 16 KB each
  const int id = blockIdx.x;
  const int b = id & 7;
  const int rest = id >> 3;
  const int xt = rest & 7;
  const int seg = rest >> 3;
  const int x0 = xt * 512;
  const int t = threadIdx.x;
  const int lane = t & 63, wave = t >> 6;
  const int xw = x0 + wave * 64;

  // A-res: proj f16, 64x (4 xf) x 256c -> 128 VGPR
  v8h Ah[4][8];
#pragma unroll
  for (int xf = 0; xf < 4; ++xf) {
    const size_t ro =
        ((size_t)b * HW + xw + xf * 16 + (lane & 15)) * CO + (lane >> 4) * 8;
#pragma unroll
    for (int st = 0; st < 8; ++st)
      Ah[xf][st] = __builtin_bit_cast(v8h, *(const uint4*)&proj_h[ro + st * 32]);
  }

  float m[4][4], d[4][4];
#pragma unroll
  for (int xf = 0; xf < 4; ++xf)
#pragma unroll
    for (int r = 0; r < 4; ++r) { m[xf][r] = -3.0e38f; d[xf][r] = 0.f; }

  auto stage = [&](int bufi, int tt) {
    const int yy0 = tt * 32;
#pragma unroll
    for (int i = 0; i < 2; ++i) {
      int G = i * 512 + t;
      int r = G >> 5, sl = G & 31;
      size_t so = ((size_t)b * HW + yy0 + r) * CO + ((sl ^ (r & 7)) << 3);
      unsigned lb = (unsigned)((i * 512 + wave * 64) << 4);
      gll16(&pem_t_h[so], &pbuf[bufi][lb]);
    }
  };

  const int tt0 = seg * SEGC;
  stage(0, tt0);
  __syncthreads();

  for (int tc = 0; tc < SEGC; ++tc) {
    if (tc + 1 < SEGC) stage((tc + 1) & 1, tt0 + tc + 1);

    const unsigned char* bp = pbuf[tc & 1];
    v4f acc[4][2];
#pragma unroll
    for (int xf = 0; xf < 4; ++xf)
#pragma unroll
      for (int yc = 0; yc < 2; ++yc) acc[xf][yc] = (v4f){0.f, 0.f, 0.f, 0.f};

#pragma unroll
    for (int st = 0; st < 8; ++st) {
#pragma unroll
      for (int yc = 0; yc < 2; ++yc) {
        v8h bh = lds_frag_h512(bp, yc * 16 + (lane & 15), st * 4 + (lane >> 4));
        acc[0][yc] = mfma16h(Ah[0][st], bh, acc[0][yc]);
        acc[1][yc] = mfma16h(Ah[1][st], bh, acc[1][yc]);
        acc[2][yc] = mfma16h(Ah[2][st], bh, acc[2][yc]);
        acc[3][yc] = mfma16h(Ah[3][st], bh, acc[3][yc]);
      }
    }

    // defer-max stats
#pragma unroll
    for (int xf = 0; xf < 4; ++xf) {
      float mx8 = fmaxf(fmaxf(fmaxf(acc[xf][0][0], acc[xf][0][1]),
                              fmaxf(acc[xf][0][2], acc[xf][0][3])),
                        fmaxf(fmaxf(acc[xf][1][0], acc[xf][1][1]),
                              fmaxf(acc[xf][1][2], acc[xf][1][3])));
      float minm = fminf(fminf(m[xf][0], m[xf][1]), fminf(m[xf][2], m[xf][3]));
      if (__any(mx8 > minm + 8.0f)) {
#pragma unroll
        for (int r = 0; r < 4; ++r) {
          float rm = fmaxf(acc[xf][0][r], acc[xf][1][r]);
          rm = fmaxf(rm, __shfl_xor(rm, 1));
          rm = fmaxf(rm, __shfl_xor(rm, 2));
          rm = fmaxf(rm, __shfl_xor(rm, 4));
          rm = fmaxf(rm, __shfl_xor(rm, 8));
          float mn = fmaxf(m[xf][r], rm);
          d[xf][r] *= __expf(m[xf][r] - mn);
          m[xf][r] = mn;
        }
      }
#pragma unroll
      for (int r = 0; r < 4; ++r)
        d[xf][r] += __expf(acc[xf][0][r] - m[xf][r]) +
                    __expf(acc[xf][1][r] - m[xf][r]);
    }
    __syncthreads();
  }

#pragma unroll
  for (int xf = 0; xf < 4; ++xf) {
    float dv[4];
#pragma unroll
    for (int r = 0; r < 4; ++r) {
      float v = d[xf][r];
      v += __shfl_xor(v, 1);
      v += __shfl_xor(v, 2);
      v += __shfl_xor(v, 4);
      v += __shfl_xor(v, 8);
      dv[r] = v;
    }
    if ((lane & 15) == 0) {
      size_t o = ((size_t)(b * NSEG + seg)) * HW + xw + xf * 16 + (lane >> 4) * 4;
      *(float4*)&m_seg[o] = make_float4(m[xf][0], m[xf][1], m[xf][2], m[xf][3]);
      *(float4*)&d_seg[o] = make_float4(dv[0], dv[1], dv[2], dv[3]);
    }
  }
}

// ===========================================================================
// Merge segments -> Cx = M + log(D)   (so P = exp(S - Cx))
// ===========================================================================
__global__ __launch_bounds__(256) void k_red2(
    const float* __restrict__ m_seg, const float* __restrict__ d_seg,
    float* __restrict__ Cx) {
  int idx = blockIdx.x * 256 + threadIdx.x;
  int b = idx >> 12;
  int xx = idx & 4095;
  float ms[NSEG], ds[NSEG];
  float mm = -3.0e38f;
#pragma unroll
  for (int s = 0; s < NSEG; ++s) {
    ms[s] = m_seg[((size_t)(b * NSEG + s)) * HW + xx];
    ds[s] = d_seg[((size_t)(b * NSEG + s)) * HW + xx];
    mm = fmaxf(mm, ms[s]);
  }
  float dd = 0.f;
#pragma unroll
  for (int s = 0; s < NSEG; ++s) dd += ds[s] * __expf(ms[s] - mm);
  Cx[(size_t)b * HW + xx] = mm + __logf(dd);
}

// ===========================================================================
// Fused out-pass (round-11 proven best): 32x32x16 MFMA, dbuf + counted-wait:
//   top: vmcnt(0)+lgkm(0)+s_barrier; issue next stage right after
//   mid: lgkmcnt(0)-only s_barrier -> gll16 stay in flight
// 512 thr (8 waves), y-tile 128, x-chunks of 64.
// grid: 8b * 32yt = 256 blocks. LDS 144 KB -> 1 block/CU, 2 waves/SIMD.
// ===========================================================================
__global__ __launch_bounds__(512, 2) void k_fused(
    const ushort_t* __restrict__ proj_h, const ushort_t* __restrict__ pem_t_h,
    const ushort_t* __restrict__ pem_h, const float* __restrict__ Cx,
    float* __restrict__ out) {
  __shared__ __align__(16) unsigned char Lp[2][64 * 512];   // proj 32KB x2
  __shared__ __align__(16) unsigned char Lk[2][256 * 128];  // pem_kx 32KB x2
  __shared__ __align__(16) unsigned char Le[128 * 128];     // E tile 16KB
  const int id = blockIdx.x;
  const int b = id & 7;
  const int yt = id >> 3;
  const int y0 = yt * 128;
  const int t = threadIdx.x;
  const int lane = t & 63, wave = t >> 6;
  const int l31 = lane & 31, lh = lane >> 5;
  const int wx = wave & 1, wy = wave >> 1;   // S tiling: 2x * 4y
  const int kq = wave & 3, yq = wave >> 2;   // PV tiling: 4k * 2y

  // B-res for S: wave's 32y slice of pem_t, K=256: 16 frags (64 VGPR)
  v8h Bres[16];
  {
    const size_t ro =
        ((size_t)b * HW + y0 + wy * 32 + l31) * CO + lh * 8;
#pragma unroll
    for (int st = 0; st < 16; ++st)
      Bres[st] = __builtin_bit_cast(v8h, *(const uint4*)&pem_t_h[ro + st * 16]);
  }

  v16f pv[2][2];
#pragma unroll
  for (int kt = 0; kt < 2; ++kt)
#pragma unroll
    for (int yy = 0; yy < 2; ++yy)
#pragma unroll
      for (int r = 0; r < 16; ++r) pv[kt][yy][r] = 0.f;

  auto stage = [&](int bufi, int xt) {
    const int x0s = xt * 64;
    // Lp: [64x][512B] = 32KB
#pragma unroll
    for (int i = 0; i < 4; ++i) {
      int G = i * 512 + t;
      int r = G >> 5, sl = G & 31;
      size_t so = ((size_t)b * HW + x0s + r) * CO + ((sl ^ (r & 7)) << 3);
      gll16(&proj_h[so], &Lp[bufi][(unsigned)((i * 512 + wave * 64) << 4)]);
    }
    // Lk: [256k][128B] = 32KB
#pragma unroll
    for (int i = 0; i < 4; ++i) {
      int G = i * 512 + t;
      int r = G >> 3, sl = G & 7;
      size_t so = ((size_t)b * CO + r) * HW + x0s + ((sl ^ (r & 7)) << 3);
      gll16(&pem_h[so], &Lk[bufi][(unsigned)((i * 512 + wave * 64) << 4)]);
    }
  };

  stage(0, 0);

  for (int xt = 0; xt < 64; ++xt) {
    const int cur = xt & 1;
    const int x0 = xt * 64;
    VMEM_BAR();   // buf[cur] complete (full-chunk-old loads); all prior ds done

    // Cx prefetch FIRST (so its wait is not a gll16 drain)
    float4 c4[4];
#pragma unroll
    for (int q = 0; q < 4; ++q)
      c4[q] = *(const float4*)&Cx[(size_t)b * HW + x0 + wx * 32 + 8 * q + 4 * lh];

    if (xt + 1 < 64) stage(cur ^ 1, xt + 1);  // full-chunk latency budget

    // ---- S phase: wave's 32x*32y tile, A from Lp, B from regs ----
    v16f s;
#pragma unroll
    for (int r = 0; r < 16; ++r) s[r] = 0.f;
    __builtin_amdgcn_s_setprio(1);
#pragma unroll
    for (int st = 0; st < 16; ++st) {
      v8h a = lds_frag_h512(Lp[cur], wx * 32 + l31, st * 2 + lh);
      s = mfma32h(a, Bres[st], s);
    }
    __builtin_amdgcn_s_setprio(0);

    // ---- E = exp(S - Cx) -> Le[y][x] (f16, 128B rows, swizzled) ----
    {
      int erow = wy * 32 + l31;
#pragma unroll
      for (int q = 0; q < 4; ++q) {
        float cc[4] = {c4[q].x, c4[q].y, c4[q].z, c4[q].w};
        v4h p;
#pragma unroll
        for (int r = 0; r < 4; ++r)
          p[r] = (_Float16)__expf(s[4 * q + r] - cc[r]);
        int gx = wx * 4 + q;
        *(uint2*)(Le + erow * 128 + ((gx ^ (erow & 7)) << 4) + lh * 8) =
            __builtin_bit_cast(uint2, p);
      }
    }
    LDS_BAR();   // E visible; S's Lp[cur] reads done; gll16 STAY in flight

    // ---- PV: wave's 64k*64y over this chunk's 64x (4 k-steps of 16) ----
    __builtin_amdgcn_s_setprio(1);
#pragma unroll
    for (int st = 0; st < 4; ++st) {
      int cb = st * 2 + lh;
      v8h e0 = lds_frag_h128(Le, yq * 64 + l31, cb);
      v8h e1 = lds_frag_h128(Le, yq * 64 + 32 + l31, cb);
      v8h a0 = lds_frag_h128(Lk[cur], kq * 64 + l31, cb);
      v8h a1 = lds_frag_h128(Lk[cur], kq * 64 + 32 + l31, cb);
      pv[0][0] = mfma32h(a0, e0, pv[0][0]);
      pv[0][1] = mfma32h(a0, e1, pv[0][1]);
      pv[1][0] = mfma32h(a1, e0, pv[1][0]);
      pv[1][1] = mfma32h(a1, e1, pv[1][1]);
    }
    __builtin_amdgcn_s_setprio(0);
  }

  // epilogue: k = kq*64 + kt*32 + (r&3)+8*(r>>2)+4*lh, y = y0+yq*64+yy*32+l31
#pragma unroll
  for (int kt = 0; kt < 2; ++kt)
#pragma unroll
    for (int yy = 0; yy < 2; ++yy)
#pragma unroll
      for (int r = 0; r < 16; ++r) {
        int k = kq * 64 + kt * 32 + (r & 3) + 8 * (r >> 2) + 4 * lh;
        int y = y0 + yq * 64 + yy * 32 + l31;
        out[((size_t)b * CO + k) * HW + y] = pv[kt][yy][r];
      }
}

// ===========================================================================
// fp32 fallback path (only if ws is too small)
// ===========================================================================
__global__ __launch_bounds__(256) void k_proj(
    const float* __restrict__ x, const float* __restrict__ W,
    const float* __restrict__ bias, float* __restrict__ proj) {
  __shared__ float As[KT][68];
  __shared__ float Bs[KT][68];
  const int i0 = blockIdx.x * 64;
  const int o0 = blockIdx.y * 64;
  const int b  = blockIdx.z;
  const int t  = threadIdx.x;
  const int tx = t & 15, ty = t >> 4;
  const float* xb = x + (size_t)b * CIN * HW;
  float acc[4][4] = {};
  for (int c0 = 0; c0 < CIN; c0 += KT) {
#pragma unroll
    for (int l = 0; l < 8; ++l) {
      int idx = t + l * 256;
      int o = idx >> 5;
      int c = idx & 31;
      As[c][o] = W[(size_t)(o0 + o) * CIN + c0 + c];
    }
#pragma unroll
    for (int l = 0; l < 2; ++l) {
      int idx4 = t + l * 256;
      int c = idx4 >> 4;
      int i4 = idx4 & 15;
      *(float4*)&Bs[c][i4 * 4] =
          *(const float4*)&xb[(size_t)(c0 + c) * HW + i0 + i4 * 4];
    }
    __syncthreads();
#pragma unroll
    for (int c = 0; c < KT; ++c) {
      float4 a  = *(const float4*)&As[c][tx * 4];
      float4 bv = *(const float4*)&Bs[c][ty * 4];
      float av[4] = {a.x, a.y, a.z, a.w};
      float bb[4] = {bv.x, bv.y, bv.z, bv.w};
#pragma unroll
      for (int u = 0; u < 4; ++u)
#pragma unroll
        for (int v = 0; v < 4; ++v) acc[u][v] += av[u] * bb[v];
    }
    __syncthreads();
  }
  float* pbout = proj + (size_t)b * CO * HW;
#pragma unroll
  for (int u = 0; u < 4; ++u) {
    int o = o0 + tx * 4 + u;
    float bsv = bias[o];
    float4 r;
    r.x = acc[u][0] + bsv; r.y = acc[u][1] + bsv;
    r.z = acc[u][2] + bsv; r.w = acc[u][3] + bsv;
    *(float4*)&pbout[(size_t)o * HW + i0 + ty * 4] = r;
  }
}

__global__ __launch_bounds__(256) void k_stats(
    const float* __restrict__ proj, const float* __restrict__ pem,
    float* __restrict__ Mx, float* __restrict__ Dinv) {
  __shared__ float As[KT][68];
  __shared__ float Bs[KT][68];
  __shared__ float MsS[64][17];
  __shared__ float DsS[64][17];
  const int x0 = blockIdx.x * 64;
  const int b  = blockIdx.y;
  const int t  = threadIdx.x;
  const int tx = t & 15, ty = t >> 4;
  const float* pj = proj + (size_t)b * CO * HW;
  const float* pe = pem + (size_t)b * CO * HW;
  float m[4], d[4];
#pragma unroll
  for (int u = 0; u < 4; ++u) { m[u] = -3.0e38f; d[u] = 0.f; }
  for (int y0 = 0; y0 < HW; y0 += 64) {
    float s[4][4] = {};
    for (int c0 = 0; c0 < CO; c0 += KT) {
#pragma unroll
      for (int l = 0; l < 2; ++l) {
        int idx4 = t + l * 256;
        int c = idx4 >> 4, w4 = idx4 & 15;
        *(float4*)&As[c][w4 * 4] =
            *(const float4*)&pj[(size_t)(c0 + c) * HW + x0 + w4 * 4];
        *(float4*)&Bs[c][w4 * 4] =
            *(const float4*)&pe[(size_t)(c0 + c) * HW + y0 + w4 * 4];
      }
      __syncthreads();
#pragma unroll
      for (int c = 0; c < KT; ++c) {
        float4 a  = *(const float4*)&As[c][tx * 4];
        float4 bv = *(const float4*)&Bs[c][ty * 4];
        float av[4] = {a.x, a.y, a.z, a.w};
        float bb[4] = {bv.x, bv.y, bv.z, bv.w};
#pragma unroll
        for (int u = 0; u < 4; ++u)
#pragma unroll
          for (int v = 0; v < 4; ++v) s[u][v] += av[u] * bb[v];
      }
      __syncthreads();
    }
#pragma unroll
    for (int u = 0; u < 4; ++u) {
      float mv = fmaxf(fmaxf(s[u][0], s[u][1]), fmaxf(s[u][2], s[u][3]));
      if (mv > m[u]) { d[u] *= __expf(m[u] - mv); m[u] = mv; }
      d[u] += __expf(s[u][0] - m[u]) + __expf(s[u][1] - m[u]) +
              __expf(s[u][2] - m[u]) + __expf(s[u][3] - m[u]);
    }
  }
#pragma unroll
  for (int u = 0; u < 4; ++u) { MsS[tx * 4 + u][ty] = m[u]; DsS[tx * 4 + u][ty] = d[u]; }
  __syncthreads();
  if (t < 64) {
    float mm = -3.0e38f;
#pragma unroll
    for (int i = 0; i < 16; ++i) mm = fmaxf(mm, MsS[t][i]);
    float dd = 0.f;
#pragma unroll
    for (int i = 0; i < 16; ++i) dd += DsS[t][i] * __expf(MsS[t][i] - mm);
    Mx[(size_t)b * HW + x0 + t]   = mm;
    Dinv[(size_t)b * HW + x0 + t] = 1.0f / dd;
  }
}

__global__ __launch_bounds__(256) void k_out(
    const float* __restrict__ proj, const float* __restrict__ pem,
    const float* __restrict__ Mx, const float* __restrict__ Dinv,
    float* __restrict__ out) {
  __shared__ float As[KT][68];
  __shared__ float Bs[KT][68];
  __shared__ float E[64][68];
  const int y0 = blockIdx.x * 64;
  const int b  = blockIdx.y;
  const int t  = threadIdx.x;
  const int tx = t & 15, ty = t >> 4;
  const int kg = t >> 3, yg = t & 7;
  const float* pj = proj + (size_t)b * CO * HW;
  const float* pe = pem + (size_t)b * CO * HW;
  const float* Mb = Mx + (size_t)b * HW;
  const float* Db = Dinv + (size_t)b * HW;
  float acc[8][8] = {};
  for (int x0 = 0; x0 < HW; x0 += 64) {
    float s[4][4] = {};
    for (int c0 = 0; c0 < CO; c0 += KT) {
#pragma unroll
      for (int l = 0; l < 2; ++l) {
        int idx4 = t + l * 256;
        int c = idx4 >> 4, w4 = idx4 & 15;
        *(float4*)&As[c][w4 * 4] =
            *(const float4*)&pj[(size_t)(c0 + c) * HW + x0 + w4 * 4];
        *(float4*)&Bs[c][w4 * 4] =
            *(const float4*)&pe[(size_t)(c0 + c) * HW + y0 + w4 * 4];
      }
      __syncthreads();
#pragma unroll
      for (int c = 0; c < KT; ++c) {
        float4 a  = *(const float4*)&As[c][tx * 4];
        float4 bv = *(const float4*)&Bs[c][ty * 4];
        float av[4] = {a.x, a.y, a.z, a.w};
        float bb[4] = {bv.x, bv.y, bv.z, bv.w};
#pragma unroll
        for (int u = 0; u < 4; ++u)
#pragma unroll
          for (int v = 0; v < 4; ++v) s[u][v] += av[u] * bb[v];
      }
      __syncthreads();
    }
#pragma unroll
    for (int u = 0; u < 4; ++u) {
      int xr = x0 + tx * 4 + u;
      float mm = Mb[xr];
      float di = Db[xr];
      E[tx * 4 + u][ty * 4 + 0] = __expf(s[u][0] - mm) * di;
      E[tx * 4 + u][ty * 4 + 1] = __expf(s[u][1] - mm) * di;
      E[tx * 4 + u][ty * 4 + 2] = __expf(s[u][2] - mm) * di;
      E[tx * 4 + u][ty * 4 + 3] = __expf(s[u][3] - mm) * di;
    }
    __syncthreads();
    for (int xi = 0; xi < 64; xi += 4) {
      float4 p[8];
#pragma unroll
      for (int u = 0; u < 8; ++u)
        p[u] = *(const float4*)&pe[(size_t)(kg * 8 + u) * HW + x0 + xi];
#pragma unroll
      for (int j = 0; j < 4; ++j) {
        float4 e0 = *(const float4*)&E[xi + j][yg * 8];
        float4 e1 = *(const float4*)&E[xi + j][yg * 8 + 4];
        float evv[8] = {e0.x, e0.y, e0.z, e0.w, e1.x, e1.y, e1.z, e1.w};
#pragma unroll
        for (int u = 0; u < 8; ++u) {
          float a = (j == 0) ? p[u].x : (j == 1) ? p[u].y : (j == 2) ? p[u].z : p[u].w;
#pragma unroll
          for (int v = 0; v < 8; ++v) acc[u][v] += a * evv[v];
        }
      }
    }
    __syncthreads();
  }
#pragma unroll
  for (int u = 0; u < 8; ++u) {
    int k = kg * 8 + u;
    float4 r0, r1;
    r0.x = acc[u][0]; r0.y = acc[u][1]; r0.z = acc[u][2]; r0.w = acc[u][3];
    r1.x = acc[u][4]; r1.y = acc[u][5]; r1.z = acc[u][6]; r1.w = acc[u][7];
    float* ob = out + ((size_t)b * CO + k) * HW + y0 + yg * 8;
    *(float4*)&ob[0] = r0;
    *(float4*)&ob[4] = r1;
  }
}

// ===========================================================================
extern "C" void kernel_launch(void* const* d_in, const int* in_sizes, int n_in,
                              void* d_out, int out_size, void* d_ws, size_t ws_size,
                              hipStream_t stream) {
  const float* x    = (const float*)d_in[0];
  const float* pem  = (const float*)d_in[1];
  const float* W    = (const float*)d_in[2];
  const float* bias = (const float*)d_in[3];
  float* out = (float*)d_out;

  const size_t NS   = (size_t)BATCH * HW * CO;       // 8.39M
  const size_t NS2  = (size_t)BATCH * HW * CIN;      // 16.78M
  const size_t HWB  = (size_t)BATCH * HW;            // 32768
  const size_t SEGN = (size_t)BATCH * NSEG * HW;     // 131072
  const size_t WN   = (size_t)CO * CIN;              // 131072

  unsigned char* basep = (unsigned char*)d_ws;
  ushort_t* proj_h   = (ushort_t*)basep;
  ushort_t* pem_t_h  = proj_h + NS;
  ushort_t* pem_h    = pem_t_h + NS;
  float*    Cxp      = (float*)(pem_h + NS);
  float*    m_seg    = Cxp + HWB;
  float*    d_seg    = m_seg + SEGN;
  ushort_t* xt_h     = (ushort_t*)(d_seg + SEGN);
  ushort_t* w_h      = xt_h + NS2;

  const size_t need = 3 * NS * 2 + HWB * 4 + 2 * SEGN * 4 + NS2 * 2 + WN * 2;

  if (ws_size < need) {
    // fp32 fallback
    float* proj = (float*)d_ws;
    float* Mx2  = proj + NS;
    float* Di2  = Mx2 + HWB;
    const size_t need_f = (NS + 2 * HWB) * sizeof(float);
    if (ws_size < need_f) return;
    k_proj <<<dim3(HW / 64, CO / 64, BATCH), 256, 0, stream>>>(x, W, bias, proj);
    k_stats<<<dim3(HW / 64, BATCH),          256, 0, stream>>>(proj, pem, Mx2, Di2);
    k_out  <<<dim3(HW / 64, BATCH),          256, 0, stream>>>(proj, pem, Mx2, Di2, out);
    return;
  }

  k_w<<<64, 256, 0, stream>>>(W, w_h);
  k_tr_x<<<dim3(HW / 64, CIN / 64, BATCH), 256, 0, stream>>>(x, xt_h);
  k_proj_mfma<<<512, 256, 0, stream>>>(xt_h, w_h, bias, proj_h);
  k_tr_pem<<<dim3(HW / 64, CO / 64, BATCH), 256, 0, stream>>>(pem, pem_t_h, pem_h);

  k_stats_f16<<<256, 512, 0, stream>>>(proj_h, pem_t_h, m_seg, d_seg);
  k_red2<<<128, 256, 0, stream>>>(m_seg, d_seg, Cxp);
  k_fused<<<256, 512, 0, stream>>>(proj_h, pem_t_h, pem_h, Cxp, out);
}